// Round 2
// baseline (903.454 us; speedup 1.0000x reference)
//
#include <hip/hip_runtime.h>
#include <hip/hip_bf16.h>
#include <cstdint>

#define GLOBAL_AS __attribute__((address_space(1)))
#define LDS_AS    __attribute__((address_space(3)))

typedef __bf16 v8bf __attribute__((ext_vector_type(8)));
typedef __bf16 v4bf __attribute__((ext_vector_type(4)));
typedef float  v4f  __attribute__((ext_vector_type(4)));

// ---------------- f32 -> bf16 conversion ----------------
__global__ void cvt_f32_bf16(const float* __restrict__ in, __bf16* __restrict__ out, int n4) {
    int i = blockIdx.x * blockDim.x + threadIdx.x;
    if (i >= n4) return;
    float4 f = ((const float4*)in)[i];
    v4bf o;
    o[0] = (__bf16)f.x; o[1] = (__bf16)f.y; o[2] = (__bf16)f.z; o[3] = (__bf16)f.w;
    ((v4bf*)out)[i] = o;
}

// 4 equal-size weight matrices -> contiguous bf16 dst (one launch instead of 4)
__global__ void cvt_w4(const float* __restrict__ w0, const float* __restrict__ w1,
                       const float* __restrict__ w2, const float* __restrict__ w3,
                       __bf16* __restrict__ dst, int n4) {
    const float* s = blockIdx.y == 0 ? w0 : blockIdx.y == 1 ? w1 : blockIdx.y == 2 ? w2 : w3;
    int i = blockIdx.x * blockDim.x + threadIdx.x;
    if (i >= n4) return;
    float4 f = ((const float4*)s)[i];
    v4bf o;
    o[0] = (__bf16)f.x; o[1] = (__bf16)f.y; o[2] = (__bf16)f.z; o[3] = (__bf16)f.w;
    ((v4bf*)(dst + (size_t)blockIdx.y * n4 * 4))[i] = o;
}

__global__ void concat_bias2(const float* __restrict__ b0, const float* __restrict__ b1,
                             float* __restrict__ dst, int n) {
    int i = blockIdx.x * blockDim.x + threadIdx.x;
    if (i < n) dst[i] = b0[i];
    else if (i < 2 * n) dst[i] = b1[i - n];
}

// ---------------- GEMM: C[m][n] = sum_k A[m][k] * B[n][k] (+biases) ----------
// 128x128 tile, BK=32, 256 threads (4 waves, 2x2), each wave 4x4 of 16x16x32 MFMA.
// blockIdx.z batches independent GEMMs via element strides sA/sB/sC.
// All dims assumed multiples of 128 (true for every call in this problem).
template <typename OutT>
__global__ void gemm_bt(const __bf16* __restrict__ A, int lda, long long sA,
                        const __bf16* __restrict__ B, int ldb, long long sB,
                        OutT* __restrict__ C, int ldc, long long sC,
                        int K,
                        const float* __restrict__ bias_col,
                        const float* __restrict__ bias_row)
{
    __shared__ __align__(16) __bf16 As[128 * 32];
    __shared__ __align__(16) __bf16 Bs[128 * 32];
    const int tid  = threadIdx.x;
    const int wave = tid >> 6, lane = tid & 63;
    const int wr = wave >> 1, wc = wave & 1;
    const int quad = lane >> 4, l15 = lane & 15;
    const int bm = blockIdx.y, bn = blockIdx.x;

    A += (long long)blockIdx.z * sA;
    B += (long long)blockIdx.z * sB;
    C += (long long)blockIdx.z * sC;

    const __bf16* Abase = A + (size_t)(bm * 128) * lda;
    const __bf16* Bbase = B + (size_t)(bn * 128) * ldb;

    v4f acc[4][4];
#pragma unroll
    for (int i = 0; i < 4; i++)
#pragma unroll
        for (int j = 0; j < 4; j++) acc[i][j] = (v4f){0.f, 0.f, 0.f, 0.f};

    const int ar = lane >> 2;        // row within a 16-row staging chunk
    const int ac = (lane & 3) * 8;   // col element offset (8 bf16 = 16B per lane)

    for (int kt = 0; kt < K; kt += 32) {
        __syncthreads();  // protect LDS from previous iteration's readers
#pragma unroll
        for (int i = 0; i < 2; i++) {
            const int r = wave * 32 + i * 16;  // wave-uniform 16-row chunk base
            __builtin_amdgcn_global_load_lds(
                (const GLOBAL_AS void*)(Abase + (size_t)(r + ar) * lda + kt + ac),
                (LDS_AS void*)(As + r * 32), 16, 0, 0);
            __builtin_amdgcn_global_load_lds(
                (const GLOBAL_AS void*)(Bbase + (size_t)(r + ar) * ldb + kt + ac),
                (LDS_AS void*)(Bs + r * 32), 16, 0, 0);
        }
        __syncthreads();  // drains vmcnt -> LDS tiles ready

        v8bf aF[4], bF[4];
#pragma unroll
        for (int i = 0; i < 4; i++)
            aF[i] = *(const v8bf*)(As + (wr * 64 + i * 16 + l15) * 32 + quad * 8);
#pragma unroll
        for (int j = 0; j < 4; j++)
            bF[j] = *(const v8bf*)(Bs + (wc * 64 + j * 16 + l15) * 32 + quad * 8);
#pragma unroll
        for (int i = 0; i < 4; i++)
#pragma unroll
            for (int j = 0; j < 4; j++)
                acc[i][j] = __builtin_amdgcn_mfma_f32_16x16x32_bf16(aF[i], bF[j], acc[i][j], 0, 0, 0);
    }

    // Epilogue: C/D layout = row: quad*4+r, col: lane&15 (m89/m91-verified)
#pragma unroll
    for (int i = 0; i < 4; i++) {
        const int row0 = bm * 128 + wr * 64 + i * 16 + quad * 4;
#pragma unroll
        for (int j = 0; j < 4; j++) {
            const int col = bn * 128 + wc * 64 + j * 16 + l15;
            const float bc = bias_col ? bias_col[col] : 0.f;
#pragma unroll
            for (int r = 0; r < 4; r++) {
                float v = acc[i][j][r] + bc;
                if (bias_row) v += bias_row[row0 + r];
                C[(size_t)(row0 + r) * ldc + col] = (OutT)v;
            }
        }
    }
}

// ---------------- row softmax: P = softmax(scale * S) , fp32 -> bf16 ----------
// One block (256 threads) per 4096-wide row.
__global__ void softmax_rows(const float* __restrict__ Sm, __bf16* __restrict__ P, float scale) {
    const int row = blockIdx.x;
    const int t = threadIdx.x;
    const int wave = t >> 6, lane = t & 63;
    const float4* src = (const float4*)(Sm + (size_t)row * 4096);
    float4 v[4];
    float m = -3.0e38f;
#pragma unroll
    for (int c = 0; c < 4; ++c) {
        v[c] = src[c * 256 + t];
        v[c].x *= scale; v[c].y *= scale; v[c].z *= scale; v[c].w *= scale;
        m = fmaxf(m, fmaxf(fmaxf(v[c].x, v[c].y), fmaxf(v[c].z, v[c].w)));
    }
#pragma unroll
    for (int o = 32; o > 0; o >>= 1) m = fmaxf(m, __shfl_xor(m, o, 64));
    __shared__ float red[8];
    if (lane == 0) red[wave] = m;
    __syncthreads();
    m = fmaxf(fmaxf(red[0], red[1]), fmaxf(red[2], red[3]));
    float s = 0.f;
#pragma unroll
    for (int c = 0; c < 4; ++c) {
        v[c].x = __expf(v[c].x - m); v[c].y = __expf(v[c].y - m);
        v[c].z = __expf(v[c].z - m); v[c].w = __expf(v[c].w - m);
        s += v[c].x + v[c].y + v[c].z + v[c].w;
    }
#pragma unroll
    for (int o = 32; o > 0; o >>= 1) s += __shfl_xor(s, o, 64);
    if (lane == 0) red[4 + wave] = s;
    __syncthreads();
    s = red[4] + red[5] + red[6] + red[7];
    const float inv = 1.f / s;
    v4bf* dst = (v4bf*)(P + (size_t)row * 4096);
#pragma unroll
    for (int c = 0; c < 4; ++c) {
        v4bf o;
        o[0] = (__bf16)(v[c].x * inv); o[1] = (__bf16)(v[c].y * inv);
        o[2] = (__bf16)(v[c].z * inv); o[3] = (__bf16)(v[c].w * inv);
        dst[c * 256 + t] = o;
    }
}

extern "C" void kernel_launch(void* const* d_in, const int* in_sizes, int n_in,
                              void* d_out, int out_size, void* d_ws, size_t ws_size,
                              hipStream_t stream)
{
    const float* x  = (const float*)d_in[0];   // [4,4096,1024]
    const float* Wq = (const float*)d_in[1];   // [1024,1024]
    const float* bq = (const float*)d_in[2];
    const float* Wk = (const float*)d_in[3];
    const float* bk = (const float*)d_in[4];
    const float* Wv = (const float*)d_in[5];
    const float* bv = (const float*)d_in[6];
    const float* Wo = (const float*)d_in[7];
    const float* bo = (const float*)d_in[8];
    float* out = (float*)d_out;

    constexpr int B = 4, S = 4096, D = 1024;
    constexpr long long MS = (long long)B * S;  // 16384 total rows
    const size_t MiB = 1ull << 20;

    // Tier selection: batched ctx GEMM needs P for all batches live (128 MiB);
    // top tier also batches scores (+256 MiB fp32) so attention core is 3 dispatches.
    const size_t base_need = 32 * MiB /*xb*/ + 8 * MiB /*weights*/ + 64 * 1024 /*bqk+slack*/
                           + 64 * MiB /*qk*/ + 32 * MiB /*vT*/;
    int tier = 0;
    if (ws_size >= base_need + 256 * MiB + 128 * MiB)      tier = 2;
    else if (ws_size >= base_need + 64 * MiB + 128 * MiB)  tier = 1;

    char* w = (char*)d_ws;
    size_t used = 0;
    auto alloc = [&](size_t bytes) -> char* {
        char* p = w + used;
        used += (bytes + 255) & ~(size_t)255;
        return p;
    };
    __bf16* xb  = (__bf16*)alloc((size_t)MS * D * 2);      // 32 MiB (reused as ctx)
    __bf16* wqb = (__bf16*)alloc(4 * (size_t)D * D * 2);   // 8 MiB: Wq|Wk|Wv|Wo contiguous
    __bf16* wvb = wqb + 2 * (size_t)D * D;
    __bf16* wob = wqb + 3 * (size_t)D * D;
    float*  bqk = (float*)alloc(2 * D * 4);                // bq|bk
    __bf16* qk  = (__bf16*)alloc((size_t)MS * 2 * D * 2);  // 64 MiB: [16384][2048] = q|k
    __bf16* vT  = (__bf16*)alloc((size_t)D * MS * 2);      // 32 MiB: [1024][16384]
    float*  sc  = (float*)alloc((tier == 2 ? (size_t)B : 1) * S * (size_t)S * 4); // 64/256 MiB
    __bf16* pb  = (__bf16*)alloc((tier >= 1 ? (size_t)B : 1) * S * (size_t)S * 2); // 32/128 MiB
    __bf16* ctx = xb;  // xb is dead after the vT GEMM; stream order makes reuse safe
    if (used > ws_size) return;  // insufficient workspace -> visible failure

    {   // x -> bf16
        int n4 = (int)(MS * D / 4);
        cvt_f32_bf16<<<(n4 + 255) / 256, 256, 0, stream>>>(x, xb, n4);
    }
    {   // all 4 weights -> contiguous bf16
        int n4 = D * D / 4;
        cvt_w4<<<dim3((n4 + 255) / 256, 4), 256, 0, stream>>>(Wq, Wk, Wv, Wo, wqb, n4);
    }
    concat_bias2<<<(2 * D + 255) / 256, 256, 0, stream>>>(bq, bk, bqk, D);

    const dim3 blk(256);
    // qk = x [Wq|Wk]^T + [bq|bk]   [16384 x 2048]  (q = cols 0..1023, k = cols 1024..2047)
    gemm_bt<__bf16><<<dim3(2 * D / 128, MS / 128), blk, 0, stream>>>(
        xb, D, 0, wqb, D, 0, qk, 2 * D, 0, D, bqk, nullptr);
    // vT[a][m] = sum_d Wv[a][d] x[m][d] + bv[a]   [1024 x 16384]
    gemm_bt<__bf16><<<dim3(MS / 128, D / 128), blk, 0, stream>>>(
        wvb, D, 0, xb, D, 0, vT, (int)MS, 0, D, nullptr, bv);

    const float scale = 0.03125f;  // 1/sqrt(1024)
    const long long qs = (long long)S * 2 * D;   // per-batch row-block stride in qk
    const long long ss = (long long)S * S;

    if (tier == 2) {
        // scores for all batches: one dispatch, grid (32,32,4)
        gemm_bt<float><<<dim3(S / 128, S / 128, B), blk, 0, stream>>>(
            qk, 2 * D, qs, qk + D, 2 * D, qs, sc, S, ss, D, nullptr, nullptr);
        softmax_rows<<<B * S, 256, 0, stream>>>(sc, pb, scale);
        gemm_bt<__bf16><<<dim3(D / 128, S / 128, B), blk, 0, stream>>>(
            pb, S, ss, vT, (int)MS, S, ctx, D, (long long)S * D, S, nullptr, nullptr);
    } else if (tier == 1) {
        for (int b = 0; b < B; ++b) {
            gemm_bt<float><<<dim3(S / 128, S / 128), blk, 0, stream>>>(
                qk + (long long)b * qs, 2 * D, 0, qk + D + (long long)b * qs, 2 * D, 0,
                sc, S, 0, D, nullptr, nullptr);
            softmax_rows<<<S, 256, 0, stream>>>(sc, pb + (long long)b * ss, scale);
        }
        gemm_bt<__bf16><<<dim3(D / 128, S / 128, B), blk, 0, stream>>>(
            pb, S, ss, vT, (int)MS, S, ctx, D, (long long)S * D, S, nullptr, nullptr);
    } else {
        for (int b = 0; b < B; ++b) {
            gemm_bt<float><<<dim3(S / 128, S / 128), blk, 0, stream>>>(
                qk + (long long)b * qs, 2 * D, 0, qk + D + (long long)b * qs, 2 * D, 0,
                sc, S, 0, D, nullptr, nullptr);
            softmax_rows<<<S, 256, 0, stream>>>(sc, pb, scale);
            gemm_bt<__bf16><<<dim3(D / 128, S / 128), blk, 0, stream>>>(
                pb, S, 0, vT + (long long)b * S, (int)MS, 0,
                ctx + (long long)b * S * D, D, 0, S, nullptr, nullptr);
        }
    }
    // out = ctx Wo^T + bo  (fp32 -> d_out)
    gemm_bt<float><<<dim3(D / 128, MS / 128), blk, 0, stream>>>(
        ctx, D, 0, wob, D, 0, out, D, 0, D, bo, nullptr);
}

// Round 3
// 701.354 us; speedup vs baseline: 1.2882x; 1.2882x over previous
//
#include <hip/hip_runtime.h>
#include <hip/hip_bf16.h>
#include <cstdint>

#define GLOBAL_AS __attribute__((address_space(1)))
#define LDS_AS    __attribute__((address_space(3)))

typedef __bf16 v8bf __attribute__((ext_vector_type(8)));
typedef __bf16 v4bf __attribute__((ext_vector_type(4)));
typedef float  v4f  __attribute__((ext_vector_type(4)));

struct P2 { __bf16* p[2]; };
struct P4 { __bf16* p[4]; };

// ---------------- shared MFMA K-loop: 128x128 tile, BK=32, 4 waves ----------
__device__ __forceinline__ void kloop(const __bf16* __restrict__ Abase, int lda,
                                      const __bf16* __restrict__ Bbase, int ldb,
                                      int K, __bf16* As, __bf16* Bs,
                                      v4f (&acc)[4][4], int wave, int lane)
{
    const int wr = wave >> 1, wc = wave & 1;
    const int quad = lane >> 4, l15 = lane & 15;
    const int ar = lane >> 2;        // row within 16-row staging chunk
    const int ac = (lane & 3) * 8;   // 8 bf16 = 16B per lane

    for (int kt = 0; kt < K; kt += 32) {
        __syncthreads();
#pragma unroll
        for (int i = 0; i < 2; i++) {
            const int r = wave * 32 + i * 16;
            __builtin_amdgcn_global_load_lds(
                (const GLOBAL_AS void*)(Abase + (size_t)(r + ar) * lda + kt + ac),
                (LDS_AS void*)(As + r * 32), 16, 0, 0);
            __builtin_amdgcn_global_load_lds(
                (const GLOBAL_AS void*)(Bbase + (size_t)(r + ar) * ldb + kt + ac),
                (LDS_AS void*)(Bs + r * 32), 16, 0, 0);
        }
        __syncthreads();

        v8bf aF[4], bF[4];
#pragma unroll
        for (int i = 0; i < 4; i++)
            aF[i] = *(const v8bf*)(As + (wr * 64 + i * 16 + l15) * 32 + quad * 8);
#pragma unroll
        for (int j = 0; j < 4; j++)
            bF[j] = *(const v8bf*)(Bs + (wc * 64 + j * 16 + l15) * 32 + quad * 8);
#pragma unroll
        for (int i = 0; i < 4; i++)
#pragma unroll
            for (int j = 0; j < 4; j++)
                acc[i][j] = __builtin_amdgcn_mfma_f32_16x16x32_bf16(aF[i], bF[j], acc[i][j], 0, 0, 0);
    }
}

// ---------------- generic GEMM: C = A * B^T (+col/row bias) ----------------
template <typename OutT>
__global__ void gemm_bt(const __bf16* __restrict__ A, int lda, long long sA,
                        const __bf16* __restrict__ B, int ldb, long long sB,
                        OutT* __restrict__ C, int ldc, long long sC,
                        int K,
                        const float* __restrict__ bias_col,
                        const float* __restrict__ bias_row)
{
    __shared__ __align__(16) __bf16 As[128 * 32];
    __shared__ __align__(16) __bf16 Bs[128 * 32];
    const int tid = threadIdx.x, wave = tid >> 6, lane = tid & 63;
    const int wr = wave >> 1, wc = wave & 1, quad = lane >> 4, l15 = lane & 15;
    const int bm = blockIdx.y, bn = blockIdx.x;
    A += (long long)blockIdx.z * sA;
    B += (long long)blockIdx.z * sB;
    C += (long long)blockIdx.z * sC;

    v4f acc[4][4];
#pragma unroll
    for (int i = 0; i < 4; i++)
#pragma unroll
        for (int j = 0; j < 4; j++) acc[i][j] = (v4f){0.f, 0.f, 0.f, 0.f};

    kloop(A + (size_t)(bm * 128) * lda, lda, B + (size_t)(bn * 128) * ldb, ldb,
          K, As, Bs, acc, wave, lane);

#pragma unroll
    for (int i = 0; i < 4; i++) {
        const int row0 = bm * 128 + wr * 64 + i * 16 + quad * 4;
#pragma unroll
        for (int j = 0; j < 4; j++) {
            const int col = bn * 128 + wc * 64 + j * 16 + l15;
            const float bc = bias_col ? bias_col[col] : 0.f;
#pragma unroll
            for (int r = 0; r < 4; r++) {
                float v = acc[i][j][r] + bc;
                if (bias_row) v += bias_row[row0 + r];
                C[(size_t)(row0 + r) * ldc + col] = (OutT)v;
            }
        }
    }
}

// ------------- scores GEMM with fused exp + row-sum atomics ----------------
// E = exp(A*B^T) as bf16 (scale pre-folded into A's weights), rowsum += partials.
__global__ void gemm_exp(const __bf16* __restrict__ A, int lda, long long sA,
                         const __bf16* __restrict__ B, int ldb, long long sB,
                         P2 Eout, int ldc,
                         float* __restrict__ rowsum, int rsStride, int K)
{
    __shared__ __align__(16) __bf16 As[128 * 32];
    __shared__ __align__(16) __bf16 Bs[128 * 32];
    const int tid = threadIdx.x, wave = tid >> 6, lane = tid & 63;
    const int wr = wave >> 1, wc = wave & 1, quad = lane >> 4, l15 = lane & 15;
    const int bm = blockIdx.y, bn = blockIdx.x;
    A += (long long)blockIdx.z * sA;
    B += (long long)blockIdx.z * sB;
    __bf16* C = Eout.p[blockIdx.z];
    float* rs = rowsum + (long long)blockIdx.z * rsStride;

    v4f acc[4][4];
#pragma unroll
    for (int i = 0; i < 4; i++)
#pragma unroll
        for (int j = 0; j < 4; j++) acc[i][j] = (v4f){0.f, 0.f, 0.f, 0.f};

    kloop(A + (size_t)(bm * 128) * lda, lda, B + (size_t)(bn * 128) * ldb, ldb,
          K, As, Bs, acc, wave, lane);

#pragma unroll
    for (int i = 0; i < 4; i++) {
        const int row0 = bm * 128 + wr * 64 + i * 16 + quad * 4;
        float part[4] = {0.f, 0.f, 0.f, 0.f};
#pragma unroll
        for (int j = 0; j < 4; j++) {
            const int col = bn * 128 + wc * 64 + j * 16 + l15;
#pragma unroll
            for (int r = 0; r < 4; r++) {
                float e = __expf(acc[i][j][r]);   // safe: |scaled score| << 88
                C[(size_t)(row0 + r) * ldc + col] = (__bf16)e;
                part[r] += e;
            }
        }
#pragma unroll
        for (int r = 0; r < 4; r++) {
#pragma unroll
            for (int off = 1; off < 16; off <<= 1)
                part[r] += __shfl_xor(part[r], off, 16);  // sum over the 16 cols in this quad
        }
        if (l15 == 0) {
#pragma unroll
            for (int r = 0; r < 4; r++) atomicAdd(&rs[row0 + r], part[r]);
        }
    }
}

// ------------- ctx GEMM: C = diag(1/rowsum) * E * V  (per-z E pointers) ----
__global__ void gemm_av(P4 Ain, int lda,
                        const __bf16* __restrict__ Bv, int ldb, long long sB,
                        __bf16* __restrict__ C, int ldc, long long sC,
                        const float* __restrict__ rowsum, int rsStride, int K)
{
    __shared__ __align__(16) __bf16 As[128 * 32];
    __shared__ __align__(16) __bf16 Bs[128 * 32];
    const int tid = threadIdx.x, wave = tid >> 6, lane = tid & 63;
    const int wr = wave >> 1, wc = wave & 1, quad = lane >> 4, l15 = lane & 15;
    const int bm = blockIdx.y, bn = blockIdx.x;
    const __bf16* A = Ain.p[blockIdx.z];
    const __bf16* B = Bv + (long long)blockIdx.z * sB;
    C += (long long)blockIdx.z * sC;
    const float* rs = rowsum + (long long)blockIdx.z * rsStride;

    v4f acc[4][4];
#pragma unroll
    for (int i = 0; i < 4; i++)
#pragma unroll
        for (int j = 0; j < 4; j++) acc[i][j] = (v4f){0.f, 0.f, 0.f, 0.f};

    kloop(A + (size_t)(bm * 128) * lda, lda, B + (size_t)(bn * 128) * ldb, ldb,
          K, As, Bs, acc, wave, lane);

#pragma unroll
    for (int i = 0; i < 4; i++) {
        const int row0 = bm * 128 + wr * 64 + i * 16 + quad * 4;
        float inv[4];
#pragma unroll
        for (int r = 0; r < 4; r++) inv[r] = 1.0f / rs[row0 + r];
#pragma unroll
        for (int j = 0; j < 4; j++) {
            const int col = bn * 128 + wc * 64 + j * 16 + l15;
#pragma unroll
            for (int r = 0; r < 4; r++)
                C[(size_t)(row0 + r) * ldc + col] = (__bf16)(acc[i][j][r] * inv[r]);
        }
    }
}

// ---------------- small helpers ----------------
__global__ void cvt_f32_bf16(const float* __restrict__ in, __bf16* __restrict__ out, int n4) {
    int i = blockIdx.x * blockDim.x + threadIdx.x;
    if (i >= n4) return;
    float4 f = ((const float4*)in)[i];
    v4bf o;
    o[0] = (__bf16)f.x; o[1] = (__bf16)f.y; o[2] = (__bf16)f.z; o[3] = (__bf16)f.w;
    ((v4bf*)out)[i] = o;
}

// 4 weight matrices -> contiguous bf16; first one scaled by wscale0 (folds 1/sqrt(A))
__global__ void cvt_w4(const float* __restrict__ w0, const float* __restrict__ w1,
                       const float* __restrict__ w2, const float* __restrict__ w3,
                       __bf16* __restrict__ dst, int n4, float wscale0) {
    const float* s = blockIdx.y == 0 ? w0 : blockIdx.y == 1 ? w1 : blockIdx.y == 2 ? w2 : w3;
    const float sc = blockIdx.y == 0 ? wscale0 : 1.f;
    int i = blockIdx.x * blockDim.x + threadIdx.x;
    if (i >= n4) return;
    float4 f = ((const float4*)s)[i];
    v4bf o;
    o[0] = (__bf16)(f.x * sc); o[1] = (__bf16)(f.y * sc);
    o[2] = (__bf16)(f.z * sc); o[3] = (__bf16)(f.w * sc);
    ((v4bf*)(dst + (size_t)blockIdx.y * n4 * 4))[i] = o;
}

__global__ void concat_bias2(const float* __restrict__ b0, const float* __restrict__ b1,
                             float* __restrict__ dst, int n, float s0) {
    int i = blockIdx.x * blockDim.x + threadIdx.x;
    if (i < n) dst[i] = b0[i] * s0;
    else if (i < 2 * n) dst[i] = b1[i - n];
}

__global__ void zero_f32(float* __restrict__ p, int n) {
    int i = blockIdx.x * blockDim.x + threadIdx.x;
    if (i < n) p[i] = 0.f;
}

extern "C" void kernel_launch(void* const* d_in, const int* in_sizes, int n_in,
                              void* d_out, int out_size, void* d_ws, size_t ws_size,
                              hipStream_t stream)
{
    const float* x  = (const float*)d_in[0];
    const float* Wq = (const float*)d_in[1];
    const float* bq = (const float*)d_in[2];
    const float* Wk = (const float*)d_in[3];
    const float* bk = (const float*)d_in[4];
    const float* Wv = (const float*)d_in[5];
    const float* bv = (const float*)d_in[6];
    const float* Wo = (const float*)d_in[7];
    const float* bo = (const float*)d_in[8];
    float* out = (float*)d_out;

    constexpr int B = 4, S = 4096, D = 1024;
    constexpr long long MS = (long long)B * S;
    constexpr float scale = 0.03125f;  // 1/sqrt(1024), exact pow2

    char* w = (char*)d_ws;
    size_t used = 0;
    auto alloc = [&](size_t bytes) -> char* {
        char* p = w + used;
        used += (bytes + 255) & ~(size_t)255;
        return p;
    };
    __bf16* xb  = (__bf16*)alloc((size_t)MS * D * 2);      // 32 MiB (later: ctx)
    __bf16* wqb = (__bf16*)alloc(4 * (size_t)D * D * 2);   // 8 MiB: sWq|Wk|Wv|Wo
    __bf16* wvb = wqb + 2 * (size_t)D * D;
    __bf16* wob = wqb + 3 * (size_t)D * D;
    float*  bqk = (float*)alloc(2 * D * 4);                // s*bq|bk
    float*  rsm = (float*)alloc((size_t)B * S * 4);        // 64 KiB row sums
    __bf16* qk  = (__bf16*)alloc((size_t)MS * 2 * D * 2);  // 64 MiB (front 32 MiB reused as E[b3])
    __bf16* vT  = (__bf16*)alloc((size_t)D * MS * 2);      // 32 MiB [1024][16384]
    __bf16* Efr = (__bf16*)alloc(3 * (size_t)S * S * 2);   // 96 MiB: E[b0..b2]
    __bf16* ctx = xb;  // xb dead after qk/vT projections
    if (used > ws_size) return;

    const long long SS = (long long)S * S;       // elements per E matrix
    const long long qs = (long long)S * 2 * D;   // qk per-batch element stride

    zero_f32<<<(B * S + 255) / 256, 256, 0, stream>>>(rsm, B * S);
    {
        int n4 = (int)(MS * D / 4);
        cvt_f32_bf16<<<(n4 + 255) / 256, 256, 0, stream>>>(x, xb, n4);
    }
    cvt_w4<<<dim3(D * D / 4 / 256, 4), 256, 0, stream>>>(Wq, Wk, Wv, Wo, wqb, D * D / 4, scale);
    concat_bias2<<<(2 * D + 255) / 256, 256, 0, stream>>>(bq, bk, bqk, D, scale);

    const dim3 blk(256);
    // qk = x [s*Wq | Wk]^T + [s*bq | bk]    [16384 x 2048]
    gemm_bt<__bf16><<<dim3(2 * D / 128, MS / 128), blk, 0, stream>>>(
        xb, D, 0, wqb, D, 0, qk, 2 * D, 0, D, bqk, nullptr);
    // vT[a][m] = Wv[a]·x[m] + bv[a]   [1024 x 16384]
    gemm_bt<__bf16><<<dim3(MS / 128, D / 128), blk, 0, stream>>>(
        wvb, D, 0, xb, D, 0, vT, (int)MS, 0, D, nullptr, bv);

    // E = exp(q k^T), pair-batched; rowsums via atomics.
    P2 e0; e0.p[0] = Efr;          e0.p[1] = Efr + SS;
    P2 e1; e1.p[0] = Efr + 2 * SS; e1.p[1] = qk;   // qk[b0,b1] rows dead after pair-0
    gemm_exp<<<dim3(S / 128, S / 128, 2), blk, 0, stream>>>(
        qk, 2 * D, qs, qk + D, 2 * D, qs, e0, S, rsm, S, D);
    gemm_exp<<<dim3(S / 128, S / 128, 2), blk, 0, stream>>>(
        qk + 2 * qs, 2 * D, qs, qk + D + 2 * qs, 2 * D, qs, e1, S, rsm + 2 * S, S, D);

    // ctx = diag(1/rowsum) E V, all 4 batches in one dispatch
    P4 ea; ea.p[0] = Efr; ea.p[1] = Efr + SS; ea.p[2] = Efr + 2 * SS; ea.p[3] = qk;
    gemm_av<<<dim3(D / 128, S / 128, B), blk, 0, stream>>>(
        ea, S, vT, (int)MS, S, ctx, D, (long long)S * D, rsm, S, S);

    // out = ctx Wo^T + bo
    gemm_bt<float><<<dim3(D / 128, MS / 128), blk, 0, stream>>>(
        ctx, D, 0, wob, D, 0, out, D, 0, D, bo, nullptr);
}

// Round 7
// 648.979 us; speedup vs baseline: 1.3921x; 1.0807x over previous
//
#include <hip/hip_runtime.h>
#include <hip/hip_bf16.h>
#include <cstdint>

#define GLOBAL_AS __attribute__((address_space(1)))
#define LDS_AS    __attribute__((address_space(3)))

typedef __bf16 v8bf __attribute__((ext_vector_type(8)));
typedef __bf16 v4bf __attribute__((ext_vector_type(4)));
typedef float  v4f  __attribute__((ext_vector_type(4)));

struct P2 { __bf16* p[2]; };
struct P4 { __bf16* p[4]; };

// --------- XCD-aware block remap, fully compile-time (flat%8 -> XCD) --------
// Gives each XCD a contiguous (z,bm) range x all bn, so blocks sharing an
// A-tile are co-resident on one XCD and its L2 absorbs the bn re-read.
// LBN/LBM/LNZ = log2 of grid dims (compile-time). Bijective for LNZ+LBM>=3.
template <int SWZ, int LBN, int LBM, int LNZ>
__device__ __forceinline__ void remap(int& bn, int& bm, int& bz) {
    if constexpr (!SWZ) {
        bn = blockIdx.x; bm = blockIdx.y; bz = blockIdx.z;
    } else {
        const unsigned f = blockIdx.x + (blockIdx.y << LBN) + (blockIdx.z << (LBN + LBM));
        const unsigned xcd = f & 7u, slot = f >> 3;
        constexpr unsigned T = (1u << (LNZ + LBM)) >> 3;   // (z,bm) pairs per XCD
        const unsigned p = xcd * T + (slot >> LBN);
        bn = (int)(slot & ((1u << LBN) - 1u));
        bm = (int)(p & ((1u << LBM) - 1u));
        bz = (int)(p >> LBM);
    }
}

// ---------------- shared MFMA K-loop: 128x128 tile, BK=32, 4 waves ----------
__device__ __forceinline__ void kloop(const __bf16* __restrict__ Abase, int lda,
                                      const __bf16* __restrict__ Bbase, int ldb,
                                      int K, __bf16* As, __bf16* Bs,
                                      v4f (&acc)[4][4], int wave, int lane)
{
    const int wr = wave >> 1, wc = wave & 1;
    const int quad = lane >> 4, l15 = lane & 15;
    const int ar = lane >> 2;        // row within 16-row staging chunk
    const int ac = (lane & 3) * 8;   // 8 bf16 = 16B per lane

    for (int kt = 0; kt < K; kt += 32) {
        __syncthreads();
#pragma unroll
        for (int i = 0; i < 2; i++) {
            const int r = wave * 32 + i * 16;
            __builtin_amdgcn_global_load_lds(
                (const GLOBAL_AS void*)(Abase + (size_t)(r + ar) * lda + kt + ac),
                (LDS_AS void*)(As + r * 32), 16, 0, 0);
            __builtin_amdgcn_global_load_lds(
                (const GLOBAL_AS void*)(Bbase + (size_t)(r + ar) * ldb + kt + ac),
                (LDS_AS void*)(Bs + r * 32), 16, 0, 0);
        }
        __syncthreads();

        v8bf aF[4], bF[4];
#pragma unroll
        for (int i = 0; i < 4; i++)
            aF[i] = *(const v8bf*)(As + (wr * 64 + i * 16 + l15) * 32 + quad * 8);
#pragma unroll
        for (int j = 0; j < 4; j++)
            bF[j] = *(const v8bf*)(Bs + (wc * 64 + j * 16 + l15) * 32 + quad * 8);
#pragma unroll
        for (int i = 0; i < 4; i++)
#pragma unroll
            for (int j = 0; j < 4; j++)
                acc[i][j] = __builtin_amdgcn_mfma_f32_16x16x32_bf16(aF[i], bF[j], acc[i][j], 0, 0, 0);
    }
}

// ---------------- generic GEMM: C = A * B^T (+col/row bias) ----------------
template <typename OutT, int SWZ, int LBN, int LBM, int LNZ>
__global__ void gemm_bt(const __bf16* __restrict__ A, int lda, long long sA,
                        const __bf16* __restrict__ B, int ldb, long long sB,
                        OutT* __restrict__ C, int ldc, long long sC,
                        int K,
                        const float* __restrict__ bias_col,
                        const float* __restrict__ bias_row)
{
    __shared__ __align__(16) __bf16 As[128 * 32];
    __shared__ __align__(16) __bf16 Bs[128 * 32];
    const int tid = threadIdx.x, wave = tid >> 6, lane = tid & 63;
    const int wr = wave >> 1, wc = wave & 1, quad = lane >> 4, l15 = lane & 15;
    int bn, bm, bz;
    remap<SWZ, LBN, LBM, LNZ>(bn, bm, bz);
    A += (long long)bz * sA;
    B += (long long)bz * sB;
    C += (long long)bz * sC;

    v4f acc[4][4];
#pragma unroll
    for (int i = 0; i < 4; i++)
#pragma unroll
        for (int j = 0; j < 4; j++) acc[i][j] = (v4f){0.f, 0.f, 0.f, 0.f};

    kloop(A + (size_t)(bm * 128) * lda, lda, B + (size_t)(bn * 128) * ldb, ldb,
          K, As, Bs, acc, wave, lane);

#pragma unroll
    for (int i = 0; i < 4; i++) {
        const int row0 = bm * 128 + wr * 64 + i * 16 + quad * 4;
#pragma unroll
        for (int j = 0; j < 4; j++) {
            const int col = bn * 128 + wc * 64 + j * 16 + l15;
            const float bc = bias_col ? bias_col[col] : 0.f;
#pragma unroll
            for (int r = 0; r < 4; r++) {
                float v = acc[i][j][r] + bc;
                if (bias_row) v += bias_row[row0 + r];
                C[(size_t)(row0 + r) * ldc + col] = (OutT)v;
            }
        }
    }
}

// ------------- scores GEMM with fused exp + row-sum atomics ----------------
// E = exp(A*B^T) as bf16 (scale pre-folded into A's weights), rowsum += partials.
template <int SWZ, int LBN, int LBM, int LNZ>
__global__ void gemm_exp(const __bf16* __restrict__ A, int lda, long long sA,
                         const __bf16* __restrict__ B, int ldb, long long sB,
                         P2 Eout, int ldc,
                         float* __restrict__ rowsum, int rsStride, int K)
{
    __shared__ __align__(16) __bf16 As[128 * 32];
    __shared__ __align__(16) __bf16 Bs[128 * 32];
    const int tid = threadIdx.x, wave = tid >> 6, lane = tid & 63;
    const int wr = wave >> 1, wc = wave & 1, quad = lane >> 4, l15 = lane & 15;
    int bn, bm, bz;
    remap<SWZ, LBN, LBM, LNZ>(bn, bm, bz);
    A += (long long)bz * sA;
    B += (long long)bz * sB;
    __bf16* C = Eout.p[bz];
    float* rs = rowsum + (long long)bz * rsStride;

    v4f acc[4][4];
#pragma unroll
    for (int i = 0; i < 4; i++)
#pragma unroll
        for (int j = 0; j < 4; j++) acc[i][j] = (v4f){0.f, 0.f, 0.f, 0.f};

    kloop(A + (size_t)(bm * 128) * lda, lda, B + (size_t)(bn * 128) * ldb, ldb,
          K, As, Bs, acc, wave, lane);

#pragma unroll
    for (int i = 0; i < 4; i++) {
        const int row0 = bm * 128 + wr * 64 + i * 16 + quad * 4;
        float part[4] = {0.f, 0.f, 0.f, 0.f};
#pragma unroll
        for (int j = 0; j < 4; j++) {
            const int col = bn * 128 + wc * 64 + j * 16 + l15;
#pragma unroll
            for (int r = 0; r < 4; r++) {
                float e = __expf(acc[i][j][r]);   // safe: |scaled score| << 88
                C[(size_t)(row0 + r) * ldc + col] = (__bf16)e;
                part[r] += e;
            }
        }
#pragma unroll
        for (int r = 0; r < 4; r++) {
#pragma unroll
            for (int off = 1; off < 16; off <<= 1)
                part[r] += __shfl_xor(part[r], off, 16);
        }
        if (l15 == 0) {
#pragma unroll
            for (int r = 0; r < 4; r++) atomicAdd(&rs[row0 + r], part[r]);
        }
    }
}

// ------------- ctx GEMM: C = diag(1/rowsum) * E * V  (per-z E pointers) ----
template <int SWZ, int LBN, int LBM, int LNZ>
__global__ void gemm_av(P4 Ain, int lda,
                        const __bf16* __restrict__ Bv, int ldb, long long sB,
                        __bf16* __restrict__ C, int ldc, long long sC,
                        const float* __restrict__ rowsum, int rsStride, int K)
{
    __shared__ __align__(16) __bf16 As[128 * 32];
    __shared__ __align__(16) __bf16 Bs[128 * 32];
    const int tid = threadIdx.x, wave = tid >> 6, lane = tid & 63;
    const int wr = wave >> 1, wc = wave & 1, quad = lane >> 4, l15 = lane & 15;
    int bn, bm, bz;
    remap<SWZ, LBN, LBM, LNZ>(bn, bm, bz);
    const __bf16* A = Ain.p[bz];
    const __bf16* B = Bv + (long long)bz * sB;
    C += (long long)bz * sC;
    const float* rs = rowsum + (long long)bz * rsStride;

    v4f acc[4][4];
#pragma unroll
    for (int i = 0; i < 4; i++)
#pragma unroll
        for (int j = 0; j < 4; j++) acc[i][j] = (v4f){0.f, 0.f, 0.f, 0.f};

    kloop(A + (size_t)(bm * 128) * lda, lda, B + (size_t)(bn * 128) * ldb, ldb,
          K, As, Bs, acc, wave, lane);

#pragma unroll
    for (int i = 0; i < 4; i++) {
        const int row0 = bm * 128 + wr * 64 + i * 16 + quad * 4;
        float inv[4];
#pragma unroll
        for (int r = 0; r < 4; r++) inv[r] = 1.0f / rs[row0 + r];
#pragma unroll
        for (int j = 0; j < 4; j++) {
            const int col = bn * 128 + wc * 64 + j * 16 + l15;
#pragma unroll
            for (int r = 0; r < 4; r++)
                C[(size_t)(row0 + r) * ldc + col] = (__bf16)(acc[i][j][r] * inv[r]);
        }
    }
}

// ---------------- small helpers ----------------
__global__ void cvt_f32_bf16(const float* __restrict__ in, __bf16* __restrict__ out, int n4) {
    int i = blockIdx.x * blockDim.x + threadIdx.x;
    if (i >= n4) return;
    float4 f = ((const float4*)in)[i];
    v4bf o;
    o[0] = (__bf16)f.x; o[1] = (__bf16)f.y; o[2] = (__bf16)f.z; o[3] = (__bf16)f.w;
    ((v4bf*)out)[i] = o;
}

__global__ void cvt_w4(const float* __restrict__ w0, const float* __restrict__ w1,
                       const float* __restrict__ w2, const float* __restrict__ w3,
                       __bf16* __restrict__ dst, int n4, float wscale0) {
    const float* s = blockIdx.y == 0 ? w0 : blockIdx.y == 1 ? w1 : blockIdx.y == 2 ? w2 : w3;
    const float sc = blockIdx.y == 0 ? wscale0 : 1.f;
    int i = blockIdx.x * blockDim.x + threadIdx.x;
    if (i >= n4) return;
    float4 f = ((const float4*)s)[i];
    v4bf o;
    o[0] = (__bf16)(f.x * sc); o[1] = (__bf16)(f.y * sc);
    o[2] = (__bf16)(f.z * sc); o[3] = (__bf16)(f.w * sc);
    ((v4bf*)(dst + (size_t)blockIdx.y * n4 * 4))[i] = o;
}

__global__ void concat_bias2(const float* __restrict__ b0, const float* __restrict__ b1,
                             float* __restrict__ dst, int n, float s0) {
    int i = blockIdx.x * blockDim.x + threadIdx.x;
    if (i < n) dst[i] = b0[i] * s0;
    else if (i < 2 * n) dst[i] = b1[i - n];
}

__global__ void zero_f32(float* __restrict__ p, int n) {
    int i = blockIdx.x * blockDim.x + threadIdx.x;
    if (i < n) p[i] = 0.f;
}

extern "C" void kernel_launch(void* const* d_in, const int* in_sizes, int n_in,
                              void* d_out, int out_size, void* d_ws, size_t ws_size,
                              hipStream_t stream)
{
    const float* x  = (const float*)d_in[0];
    const float* Wq = (const float*)d_in[1];
    const float* bq = (const float*)d_in[2];
    const float* Wk = (const float*)d_in[3];
    const float* bk = (const float*)d_in[4];
    const float* Wv = (const float*)d_in[5];
    const float* bv = (const float*)d_in[6];
    const float* Wo = (const float*)d_in[7];
    const float* bo = (const float*)d_in[8];
    float* out = (float*)d_out;

    constexpr int B = 4, S = 4096, D = 1024;
    constexpr long long MS = (long long)B * S;
    constexpr float scale = 0.03125f;  // 1/sqrt(1024), exact pow2

    char* w = (char*)d_ws;
    size_t used = 0;
    auto alloc = [&](size_t bytes) -> char* {
        char* p = w + used;
        used += (bytes + 255) & ~(size_t)255;
        return p;
    };
    __bf16* xb  = (__bf16*)alloc((size_t)MS * D * 2);      // 32 MiB (later: ctx)
    __bf16* wqb = (__bf16*)alloc(4 * (size_t)D * D * 2);   // 8 MiB: sWq|Wk|Wv|Wo
    __bf16* wvb = wqb + 2 * (size_t)D * D;
    __bf16* wob = wqb + 3 * (size_t)D * D;
    float*  bqk = (float*)alloc(2 * D * 4);                // s*bq|bk
    float*  rsm = (float*)alloc((size_t)B * S * 4);        // 64 KiB row sums
    __bf16* qk  = (__bf16*)alloc((size_t)MS * 2 * D * 2);  // 64 MiB (front 32 MiB reused as E[b3])
    __bf16* vT  = (__bf16*)alloc((size_t)D * MS * 2);      // 32 MiB [1024][16384]
    __bf16* Efr = (__bf16*)alloc(3 * (size_t)S * S * 2);   // 96 MiB: E[b0..b2]
    __bf16* ctx = xb;  // xb dead after qk/vT projections
    if (used > ws_size) return;

    const long long SS = (long long)S * S;
    const long long qs = (long long)S * 2 * D;

    zero_f32<<<(B * S + 255) / 256, 256, 0, stream>>>(rsm, B * S);
    {
        int n4 = (int)(MS * D / 4);
        cvt_f32_bf16<<<(n4 + 255) / 256, 256, 0, stream>>>(x, xb, n4);
    }
    cvt_w4<<<dim3(D * D / 4 / 256, 4), 256, 0, stream>>>(Wq, Wk, Wv, Wo, wqb, D * D / 4, scale);
    concat_bias2<<<(2 * D + 255) / 256, 256, 0, stream>>>(bq, bk, bqk, D, scale);

    const dim3 blk(256);
    // qk = x [s*Wq | Wk]^T + [s*bq | bk]  [16384 x 2048]  grid (16,128,1) swizzled
    gemm_bt<__bf16, 1, 4, 7, 0><<<dim3(2 * D / 128, MS / 128), blk, 0, stream>>>(
        xb, D, 0, wqb, D, 0, qk, 2 * D, 0, D, bqk, nullptr);
    // vT[a][m] = Wv[a]·x[m] + bv[a]   [1024 x 16384]  (natural mapping already local)
    gemm_bt<__bf16, 0, 0, 0, 0><<<dim3(MS / 128, D / 128), blk, 0, stream>>>(
        wvb, D, 0, xb, D, 0, vT, (int)MS, 0, D, nullptr, bv);

    // E = exp(q k^T), pair-batched; rowsums via atomics.  grid (32,32,2) swizzled
    P2 e0; e0.p[0] = Efr;          e0.p[1] = Efr + SS;
    P2 e1; e1.p[0] = Efr + 2 * SS; e1.p[1] = qk;   // qk[b0,b1] rows dead after pair-0
    gemm_exp<1, 5, 5, 1><<<dim3(S / 128, S / 128, 2), blk, 0, stream>>>(
        qk, 2 * D, qs, qk + D, 2 * D, qs, e0, S, rsm, S, D);
    gemm_exp<1, 5, 5, 1><<<dim3(S / 128, S / 128, 2), blk, 0, stream>>>(
        qk + 2 * qs, 2 * D, qs, qk + D + 2 * qs, 2 * D, qs, e1, S, rsm + 2 * S, S, D);

    // ctx = diag(1/rowsum) E V, all 4 batches  grid (8,32,4) swizzled
    P4 ea; ea.p[0] = Efr; ea.p[1] = Efr + SS; ea.p[2] = Efr + 2 * SS; ea.p[3] = qk;
    gemm_av<1, 3, 5, 2><<<dim3(D / 128, S / 128, B), blk, 0, stream>>>(
        ea, S, vT, (int)MS, S, ctx, D, (long long)S * D, rsm, S, S);

    // out = ctx Wo^T + bo   grid (8,128,1) swizzled
    gemm_bt<float, 1, 3, 7, 0><<<dim3(D / 128, MS / 128), blk, 0, stream>>>(
        ctx, D, 0, wob, D, 0, out, D, 0, D, bo, nullptr);
}